// Round 6
// baseline (157.873 us; speedup 1.0000x reference)
//
#include <hip/hip_runtime.h>

#define DATA_BITS 108
#define SHIFT_BITS 7
#define F4_PER_ROW 27      // 108 floats = 27 float4; rows are 432B so row starts are 16B-aligned
#define RPT 256            // rows per tile == block threads

typedef float f32x4 __attribute__((ext_vector_type(4)));

// out[b][i] = (i + S[b] < 108) ? X[b][i + S[b]] : 0
// R3 structure (best so far): divergent skip branch for OOB units, aligned lo/hi
// dwordx4 loads + register blend. This round: plain stores (no NT) and a
// compile-time 27-trip full-tile loop so the compiler can unroll/interleave.
__global__ __launch_bounds__(RPT) void barrel_fused_kernel(
    const float* __restrict__ X,
    const int* __restrict__ shift,
    float* __restrict__ out, int rows) {

    __shared__ int sS[RPT];

    const int row0 = blockIdx.x * RPT;
    const int t = threadIdx.x;
    const int N = rows * DATA_BITS;          // 108,000,000 (fits int32)

    // ---- phase 1: collapse 7 shift bits (layer 0 = MSB) -> sS
    const int r = row0 + t;
    if (r < rows) {
        const int* p = shift + r * SHIFT_BITS;
        int s = 0;
        #pragma unroll
        for (int l = 0; l < SHIFT_BITS; ++l) s = (s << 1) | (p[l] & 1);
        sS[t] = s;
    }
    __syncthreads();

    // one output unit (float4) — branchy: OOB units skip loads entirely
    auto process = [&](int u) {
        const int rb = u / F4_PER_ROW;               // constant divisor -> magic mul
        const int q  = u - rb * F4_PER_ROW;
        const int s  = sS[rb];
        const int valid = DATA_BITS - s;             // may be <= 0 (s up to 127)
        const int i0 = q * 4;
        const int rowbase = (row0 + rb) * DATA_BITS;

        f32x4 rv = {0.f, 0.f, 0.f, 0.f};
        if (i0 < valid) {
            const int s_al = s & ~3;
            const int m    = s & 3;
            const int idx_lo = rowbase + i0 + s_al;  // 16B-aligned
            const int idx_hi = min(idx_lo + 4, N - 4);  // final-row clamp; clamped elems tail-masked
            const f32x4 lo = *reinterpret_cast<const f32x4*>(X + idx_lo);
            const f32x4 hi = *reinterpret_cast<const f32x4*>(X + idx_hi);
            // branchless blend: rv[j] = w[m + j], w = {lo, hi}
            const bool m2 = (m & 2) != 0;
            const bool m1 = (m & 1) != 0;
            const float t0 = m2 ? lo[2] : lo[0];
            const float t1 = m2 ? lo[3] : lo[1];
            const float t2 = m2 ? hi[0] : lo[2];
            const float t3 = m2 ? hi[1] : lo[3];
            const float t4 = m2 ? hi[2] : hi[0];
            rv[0] = m1 ? t1 : t0;
            rv[1] = m1 ? t2 : t1;
            rv[2] = m1 ? t3 : t2;
            rv[3] = m1 ? t4 : t3;
            // zero-mask the src >= 108 tail
            rv[0] = (i0 + 0 < valid) ? rv[0] : 0.f;
            rv[1] = (i0 + 1 < valid) ? rv[1] : 0.f;
            rv[2] = (i0 + 2 < valid) ? rv[2] : 0.f;
            rv[3] = (i0 + 3 < valid) ? rv[3] : 0.f;
        }
        *reinterpret_cast<f32x4*>(out + rowbase + i0) = rv;   // plain store (L2 write-back)
    };

    const int nrows = min(RPT, rows - row0);
    if (nrows == RPT) {
        // full tile: compile-time trip count, modest unroll for scheduling room
        #pragma unroll 2
        for (int k = 0; k < F4_PER_ROW; ++k) process(t + k * RPT);
    } else {
        const int units = nrows * F4_PER_ROW;
        for (int u = t; u < units; u += RPT) process(u);
    }
}

extern "C" void kernel_launch(void* const* d_in, const int* in_sizes, int n_in,
                              void* d_out, int out_size, void* d_ws, size_t ws_size,
                              hipStream_t stream) {
    const float* X     = (const float*)d_in[0];
    const int*   shift = (const int*)d_in[1];
    float*       out   = (float*)d_out;

    const int rows = in_sizes[1] / SHIFT_BITS;              // 1,000,000
    const int grid = (rows + RPT - 1) / RPT;                // 3907

    barrel_fused_kernel<<<grid, RPT, 0, stream>>>(X, shift, out, rows);
}

// Round 7
// 141.305 us; speedup vs baseline: 1.1173x; 1.1173x over previous
//
#include <hip/hip_runtime.h>

#define DATA_BITS 108
#define SHIFT_BITS 7
#define F4_PER_ROW 27      // 108 floats = 27 float4; rows are 432B so row starts are 16B-aligned
#define ROWS_PER_TILE 256  // one row per thread for the S-collapse phase

typedef float f32x4 __attribute__((ext_vector_type(4)));

// out[b][i] = (i + S[b] < 108) ? X[b][i + S[b]] : 0
// Best-known structure (R3): divergent skip branch for fully-OOB units (preserves
// line-granular prefix-skip fetch savings), per-row-uniform misalignment handled by
// a branchless blend of two overlapping ALIGNED dwordx4 windows, NT float4 stores.
__global__ __launch_bounds__(ROWS_PER_TILE) void barrel_fused_kernel(
    const float* __restrict__ X,
    const int* __restrict__ shift,
    float* __restrict__ out, int rows) {
    __shared__ int sS[ROWS_PER_TILE];

    const int row0 = blockIdx.x * ROWS_PER_TILE;
    const int t = threadIdx.x;
    const int N = rows * DATA_BITS;                 // 108,000,000 (fits int32)

    // Phase 1: collapse 7 shift bits -> S for this block's rows (MSB-first).
    const int r = row0 + t;
    if (r < rows) {
        const int* p = shift + r * SHIFT_BITS;
        int s = 0;
        #pragma unroll
        for (int l = 0; l < SHIFT_BITS; ++l) s = (s << 1) | (p[l] & 1);
        sS[t] = s;
    }
    __syncthreads();

    // Phase 2: nrows*27 float4 output units; 256 threads sweep them coalesced.
    const int nrows = min(ROWS_PER_TILE, rows - row0);
    const int units = nrows * F4_PER_ROW;
    for (int u = t; u < units; u += ROWS_PER_TILE) {
        const int rb = u / F4_PER_ROW;              // constant divisor -> magic mul
        const int q  = u - rb * F4_PER_ROW;
        const int s  = sS[rb];
        const int valid = DATA_BITS - s;            // #live output elems this row (may be <=0)
        const int i0 = q * 4;

        f32x4 rv = {0.f, 0.f, 0.f, 0.f};
        if (i0 < valid) {                           // fully-OOB units skip loads entirely
            const int s_al = s & ~3;
            const int m    = s & 3;
            const int idx_lo = (row0 + rb) * DATA_BITS + i0 + s_al;   // 16B-aligned
            int idx_hi = idx_lo + 4;
            idx_hi = min(idx_hi, N - 4);            // only engages on the final row; clamped
                                                    // elems are provably tail-masked below
            const f32x4 lo = *reinterpret_cast<const f32x4*>(X + idx_lo);
            const f32x4 hi = *reinterpret_cast<const f32x4*>(X + idx_hi);

            // branchless blend: r[j] = w[m + j], w = {lo, hi}
            const bool m2 = (m & 2) != 0;
            const bool m1 = (m & 1) != 0;
            const float t0 = m2 ? lo[2] : lo[0];
            const float t1 = m2 ? lo[3] : lo[1];
            const float t2 = m2 ? hi[0] : lo[2];
            const float t3 = m2 ? hi[1] : lo[3];
            const float t4 = m2 ? hi[2] : hi[0];
            rv[0] = m1 ? t1 : t0;
            rv[1] = m1 ? t2 : t1;
            rv[2] = m1 ? t3 : t2;
            rv[3] = m1 ? t4 : t3;

            // zero-mask the src >= 108 tail
            rv[0] = (i0 + 0 < valid) ? rv[0] : 0.f;
            rv[1] = (i0 + 1 < valid) ? rv[1] : 0.f;
            rv[2] = (i0 + 2 < valid) ? rv[2] : 0.f;
            rv[3] = (i0 + 3 < valid) ? rv[3] : 0.f;
        }
        f32x4* dst = reinterpret_cast<f32x4*>(out + (long long)(row0 + rb) * DATA_BITS + i0);
        __builtin_nontemporal_store(rv, dst);       // streaming write: don't pollute L2
    }
}

extern "C" void kernel_launch(void* const* d_in, const int* in_sizes, int n_in,
                              void* d_out, int out_size, void* d_ws, size_t ws_size,
                              hipStream_t stream) {
    const float* X     = (const float*)d_in[0];
    const int*   shift = (const int*)d_in[1];
    float*       out   = (float*)d_out;

    const int rows = in_sizes[1] / SHIFT_BITS;                      // 1,000,000
    const int grid = (rows + ROWS_PER_TILE - 1) / ROWS_PER_TILE;    // 3907

    barrel_fused_kernel<<<grid, ROWS_PER_TILE, 0, stream>>>(X, shift, out, rows);
}